// Round 3
// baseline (104.692 us; speedup 1.0000x reference)
//
#include <hip/hip_runtime.h>

#define N_GENES 768
#define H 128
#define TILE 48      // 48x48 pair tile per block -> 16x16 = 256 blocks exactly
#define LDP 132      // f32 LDS row stride: +4 keeps 16B alignment, breaks bank aliasing
#define AFFP 49      // aff LDS tile stride (odd -> bank-friendly scalar reads)

typedef float    f2    __attribute__((ext_vector_type(2)));
typedef float    f32x4 __attribute__((ext_vector_type(4)));
typedef _Float16 h8    __attribute__((ext_vector_type(8)));

// ---------------------------------------------------------------------------
// Kernel A: per-gene projections. f64 accumulate for AiB/Bjp (bit-identical
// per-element k-order to R1/R2 -> argmax inputs unchanged). Y is f32 (feeds
// affinity only). Also emits f16 copies Yh/Xh for the MFMA affinity GEMM and
// the W2-difference vectors Wd (same f32 expressions as R2's sW -> same bits).
// 384 blocks x 128 threads, 2 genes/block -> 4 waves/CU on half the CUs.
// ---------------------------------------------------------------------------
__global__ __launch_bounds__(128) void grn_pre(
    const float* __restrict__ X, const float* __restrict__ W1,
    const float* __restrict__ b1, const float* __restrict__ Wb,
    const float* __restrict__ W2,
    float* __restrict__ AiB, float* __restrict__ Bjp, float* __restrict__ Wd,
    _Float16* __restrict__ Yh, _Float16* __restrict__ Xh)
{
    const int m  = threadIdx.x;       // 0..127
    const int g0 = blockIdx.x * 2;    // first gene row (384 blocks x 2 genes)

    __shared__ float Xs[2][H];
    #pragma unroll
    for (int r = 0; r < 2; ++r) Xs[r][m] = X[(g0 + r) * H + m];
    __syncthreads();

    double aib[2] = {0, 0}, bj[2] = {0, 0};
    float  y[2]   = {0.0f, 0.0f};
    const float4* W1a = (const float4*)(W1 + m * (2 * H));
    const float4* W1b = (const float4*)(W1 + m * (2 * H) + H);

    #pragma unroll 4
    for (int kq = 0; kq < H / 4; ++kq) {
        float4 wa = W1a[kq];
        float4 wb = W1b[kq];
        float wc[4];
        #pragma unroll
        for (int e = 0; e < 4; ++e) wc[e] = Wb[(kq * 4 + e) * H + m];  // coalesced across m
        const float* wae = &wa.x;
        const float* wbe = &wb.x;
        #pragma unroll
        for (int r = 0; r < 2; ++r) {
            float4 xr = *(const float4*)&Xs[r][kq * 4];
            const float* xe = &xr.x;
            #pragma unroll
            for (int e = 0; e < 4; ++e) {
                aib[r] += (double)xe[e] * (double)wae[e];
                bj[r]  += (double)xe[e] * (double)wbe[e];
                y[r]    = fmaf(xe[e], wc[e], y[r]);
            }
        }
    }

    const double b1m = (double)b1[m];
    #pragma unroll
    for (int r = 0; r < 2; ++r) {
        AiB[(g0 + r) * H + m] = (float)(aib[r] + b1m);
        Bjp[(g0 + r) * H + m] = (float)bj[r];
        Yh [(g0 + r) * H + m] = (_Float16)y[r];
        Xh [(g0 + r) * H + m] = (_Float16)Xs[r][m];
    }

    if (blockIdx.x == 0) {
        Wd[m]     = W2[m] - W2[2 * H + m];  // u-weights: W2[0]-W2[2]
        Wd[H + m] = W2[m] - W2[H + m];      // v-weights: W2[0]-W2[1]
    }
}

// f32 tile loader: 48 rows x 128 floats (1536 float4) by 256 threads, coalesced.
__device__ __forceinline__ void load_tile_f32(float* __restrict__ dst,
                                              const float* __restrict__ src, int tx)
{
    #pragma unroll
    for (int t = 0; t < 6; ++t) {
        int idx = tx + t * 256;       // 0..1535
        int row = idx >> 5;           // 32 float4 per row
        int c4  = idx & 31;
        *(float4*)&dst[row * LDP + c4 * 4] = *(const float4*)&src[row * H + c4 * 4];
    }
}

// ---------------------------------------------------------------------------
// Kernel B: fused main. 256 blocks (one/CU), 256 threads, 3x3 pairs/thread.
// Stage 1 (pre-sync): stage AiB/Bjp tiles into LDS; concurrently compute the
//   48x48 affinity tile via f16 MFMA (9 16x16 tiles over 4 waves), operands
//   gathered from global Yh/Xh (A[m=lane&15][k=quad*8+j] / gemm_bt pattern),
//   D written to affS in C-layout (col=lane&15, row=quad*4+reg).
// Stage 2: u=l0-l2, v=l0-l1 with h=relu(a+b) packed f32 (bit-identical h),
//   scalar fma chains in the exact R1/R2 order; w from global Wd (off LDS pipe).
// ---------------------------------------------------------------------------
__global__ __launch_bounds__(256) void grn_main(
    const float* __restrict__ AiB, const float* __restrict__ Bjp,
    const _Float16* __restrict__ Yh, const _Float16* __restrict__ Xh,
    const float* __restrict__ Wd,  const float* __restrict__ b2,
    const float* __restrict__ bb,  float* __restrict__ out)
{
    const int gj = blockIdx.x & 15;
    const int gi = blockIdx.x >> 4;
    const int tx = threadIdx.x;
    const int it = tx >> 4;   // 0..15 -> i rows it+{0,16,32}
    const int jt = tx & 15;   // 0..15 -> j cols jt+{0,16,32}

    __shared__ float sL[TILE * LDP];     // AiB tile
    __shared__ float sR[TILE * LDP];     // Bjp tile
    __shared__ float affS[TILE * AFFP];  // affinity tile

    // ---- stage AiB/Bjp tiles ----
    load_tile_f32(sL, AiB + gi * TILE * H, tx);
    load_tile_f32(sR, Bjp + gj * TILE * H, tx);

    // ---- affinity via MFMA: wave wv handles 16x16 tiles t = wv, wv+4, wv+8 ----
    {
        const int lane = tx & 63;
        const int wv   = tx >> 6;
        const int lrow = lane & 15;   // A/B fragment row, D col
        const int lq   = lane >> 4;   // quad: k-offset lq*8, D rows lq*4..lq*4+3
        for (int t = wv; t < 9; t += 4) {
            const int tr = t / 3, tc = t % 3;
            const _Float16* ya = Yh + (gi * TILE + tr * 16 + lrow) * H + lq * 8;
            const _Float16* xb = Xh + (gj * TILE + tc * 16 + lrow) * H + lq * 8;
            f32x4 a = {0.0f, 0.0f, 0.0f, 0.0f};
            #pragma unroll
            for (int k0 = 0; k0 < 4; ++k0)
                a = __builtin_amdgcn_mfma_f32_16x16x32_f16(
                        *(const h8*)(ya + k0 * 32), *(const h8*)(xb + k0 * 32), a, 0, 0, 0);
            #pragma unroll
            for (int j = 0; j < 4; ++j)
                affS[(tr * 16 + lq * 4 + j) * AFFP + tc * 16 + lrow] = a[j];
        }
    }

    __syncthreads();

    // ---- phase 2: logit differences (u/v math bit-identical to R2) ----
    const float u0 = b2[0] - b2[2];
    const float v0 = b2[0] - b2[1];
    float u[3][3], v[3][3];
    #pragma unroll
    for (int r = 0; r < 3; ++r)
        #pragma unroll
        for (int c = 0; c < 3; ++c) { u[r][c] = u0; v[r][c] = v0; }

    const f2 zero2 = {0.0f, 0.0f};
    const float4* Wd4 = (const float4*)Wd;   // [0..31]=u-weights, [32..63]=v-weights
    #pragma unroll 4
    for (int mq = 0; mq < H / 4; ++mq) {
        float4 w0 = Wd4[mq];        // uniform address -> scalar/L1-broadcast load
        float4 w1 = Wd4[32 + mq];
        float4 av[3], bv[3];
        #pragma unroll
        for (int r = 0; r < 3; ++r) av[r] = *(const float4*)&sL[(it + 16 * r) * LDP + mq * 4];
        #pragma unroll
        for (int c = 0; c < 3; ++c) bv[c] = *(const float4*)&sR[(jt + 16 * c) * LDP + mq * 4];
        #pragma unroll
        for (int r = 0; r < 3; ++r) {
            f2 a01 = {av[r].x, av[r].y};
            f2 a23 = {av[r].z, av[r].w};
            #pragma unroll
            for (int c = 0; c < 3; ++c) {
                f2 b01 = {bv[c].x, bv[c].y};
                f2 b23 = {bv[c].z, bv[c].w};
                // packed relu(a+b): elementwise -> bit-identical to scalar
                f2 h01 = __builtin_elementwise_max(a01 + b01, zero2);
                f2 h23 = __builtin_elementwise_max(a23 + b23, zero2);
                // scalar FMA chains in the exact R1/R2 m-order (tie safety)
                float uu = u[r][c], vv = v[r][c];
                uu = fmaf(h01.x, w0.x, uu); vv = fmaf(h01.x, w1.x, vv);
                uu = fmaf(h01.y, w0.y, uu); vv = fmaf(h01.y, w1.y, vv);
                uu = fmaf(h23.x, w0.z, uu); vv = fmaf(h23.x, w1.z, vv);
                uu = fmaf(h23.y, w0.w, uu); vv = fmaf(h23.y, w1.w, vv);
                u[r][c] = uu; v[r][c] = vv;
            }
        }
    }

    // ---- epilogue: sign select, bilinear bias, zero diagonal ----
    const float bbv = bb[0];
    #pragma unroll
    for (int r = 0; r < 3; ++r) {
        const int i = gi * TILE + it + 16 * r;
        #pragma unroll
        for (int c = 0; c < 3; ++c) {
            const int j = gj * TILE + jt + 16 * c;
            float A = affS[(it + 16 * r) * AFFP + (jt + 16 * c)] + bbv;
            float uu = u[r][c], vv = v[r][c];
            // cls0: vv>=0 && uu>=0 -> +A ; cls2: uu<0 && uu<vv -> -A ; else 0
            float s = (uu >= 0.0f && vv >= 0.0f) ? A
                    : ((uu < 0.0f && uu < vv) ? -A : 0.0f);
            if (i == j) s = 0.0f;
            out[i * N_GENES + j] = s;
        }
    }
}

extern "C" void kernel_launch(void* const* d_in, const int* in_sizes, int n_in,
                              void* d_out, int out_size, void* d_ws, size_t ws_size,
                              hipStream_t stream)
{
    const float* X  = (const float*)d_in[0];  // [768,128]
    const float* W1 = (const float*)d_in[1];  // [128,256]
    const float* b1 = (const float*)d_in[2];  // [128]
    const float* W2 = (const float*)d_in[3];  // [3,128]
    const float* b2 = (const float*)d_in[4];  // [3]
    const float* Wb = (const float*)d_in[5];  // [1,128,128]
    const float* bb = (const float*)d_in[6];  // [1]
    float* out = (float*)d_out;

    float* ws = (float*)d_ws;
    float*    AiB = ws;                               // 768*128 f32
    float*    Bjp = ws + N_GENES * H;                 // 768*128 f32
    float*    Wd  = ws + 2 * N_GENES * H;             // 256 f32
    _Float16* Yh  = (_Float16*)(ws + 2 * N_GENES * H + 256);   // 768*128 f16
    _Float16* Xh  = Yh + N_GENES * H;                           // 768*128 f16

    grn_pre <<<N_GENES / 2, 128, 0, stream>>>(X, W1, b1, Wb, W2, AiB, Bjp, Wd, Yh, Xh);
    grn_main<<<256,         256, 0, stream>>>(AiB, Bjp, Yh, Xh, Wd, b2, bb, out);
}

// Round 4
// 90.454 us; speedup vs baseline: 1.1574x; 1.1574x over previous
//
#include <hip/hip_runtime.h>

#define N_GENES 768
#define H 128
#define TILE 48      // 48x48 pair tile per block -> 16x16 = 256 blocks exactly
#define LDP 132      // f32 LDS row stride: +4 keeps 16B alignment, breaks bank aliasing
#define LDPH 136     // f16 LDS row stride in halves: 272B rows, 16B-aligned

typedef float    f2 __attribute__((ext_vector_type(2)));
typedef _Float16 h2 __attribute__((ext_vector_type(2)));
typedef _Float16 h8 __attribute__((ext_vector_type(8)));

// ---------------------------------------------------------------------------
// Kernel A: per-gene projections — R2-exact math (f64 accumulate, 3 rows,
// 256 blocks -> AiB/Bjp/Yh/Xh bit-identical to R2) + interleaved W2-diff
// vector Wd: Wd[2m] = W2[0][m]-W2[2][m] (u), Wd[2m+1] = W2[0][m]-W2[1][m] (v).
// ---------------------------------------------------------------------------
__global__ __launch_bounds__(128) void grn_pre(
    const float* __restrict__ X, const float* __restrict__ W1,
    const float* __restrict__ b1, const float* __restrict__ Wb,
    const float* __restrict__ W2,
    float* __restrict__ AiB, float* __restrict__ Bjp, float* __restrict__ Wd,
    _Float16* __restrict__ Yh, _Float16* __restrict__ Xh)
{
    const int m  = threadIdx.x;       // 0..127
    const int g0 = blockIdx.x * 3;    // first gene row of this block (256 blocks)

    __shared__ float Xs[3][H];
    #pragma unroll
    for (int r = 0; r < 3; ++r) Xs[r][m] = X[(g0 + r) * H + m];
    __syncthreads();

    double aib[3] = {0, 0, 0}, bj[3] = {0, 0, 0}, y[3] = {0, 0, 0};
    const float4* W1a = (const float4*)(W1 + m * (2 * H));
    const float4* W1b = (const float4*)(W1 + m * (2 * H) + H);

    #pragma unroll 4
    for (int kq = 0; kq < H / 4; ++kq) {
        float4 wa = W1a[kq];
        float4 wb = W1b[kq];
        float wc[4];
        #pragma unroll
        for (int e = 0; e < 4; ++e) wc[e] = Wb[(kq * 4 + e) * H + m];  // coalesced across m
        const float* wae = &wa.x;
        const float* wbe = &wb.x;
        #pragma unroll
        for (int r = 0; r < 3; ++r) {
            float4 xr = *(const float4*)&Xs[r][kq * 4];
            const float* xe = &xr.x;
            #pragma unroll
            for (int e = 0; e < 4; ++e) {
                aib[r] += (double)xe[e] * (double)wae[e];
                bj[r]  += (double)xe[e] * (double)wbe[e];
                y[r]   += (double)xe[e] * (double)wc[e];
            }
        }
    }

    const double b1m = (double)b1[m];
    #pragma unroll
    for (int r = 0; r < 3; ++r) {
        AiB[(g0 + r) * H + m] = (float)(aib[r] + b1m);
        Bjp[(g0 + r) * H + m] = (float)bj[r];
        Yh [(g0 + r) * H + m] = (_Float16)(float)y[r];
        Xh [(g0 + r) * H + m] = (_Float16)Xs[r][m];
    }

    if (blockIdx.x == 0) {
        Wd[2 * m]     = W2[m] - W2[2 * H + m];  // u-weight (same f32 expr as R2 sW)
        Wd[2 * m + 1] = W2[m] - W2[H + m];      // v-weight
    }
}

// f32 tile loader: 48 rows x 128 floats (1536 float4) by 256 threads, coalesced.
__device__ __forceinline__ void load_tile_f32(float* __restrict__ dst,
                                              const float* __restrict__ src, int tx)
{
    #pragma unroll
    for (int t = 0; t < 6; ++t) {
        int idx = tx + t * 256;       // 0..1535
        int row = idx >> 5;           // 32 float4 per row
        int c4  = idx & 31;
        *(float4*)&dst[row * LDP + c4 * 4] = *(const float4*)&src[row * H + c4 * 4];
    }
}

// f16 tile loader: 48 rows x 128 halves (768 x 16B) by 256 threads.
__device__ __forceinline__ void load_tile_f16(_Float16* __restrict__ dst,
                                              const _Float16* __restrict__ src, int tx)
{
    #pragma unroll
    for (int t = 0; t < 3; ++t) {
        int idx = tx + t * 256;       // 0..767
        int row = idx >> 4;           // 16 h8 per row
        int c8  = idx & 15;
        *(h8*)&dst[row * LDPH + c8 * 8] = *(const h8*)&src[row * H + c8 * 8];
    }
}

__device__ __forceinline__ h2 hpair(h8 v, int p) { h2 r; r.x = v[2*p]; r.y = v[2*p+1]; return r; }

// ---------------------------------------------------------------------------
// Kernel B: fused main. 256 blocks (one/CU), 256 threads, 3x3 pairs/thread.
// Single barrier: stage Yh/Xh (f16) + Bjp (f32) tiles, sync once.
// Phase 1: affinity via f16 v_dot2 from LDS (R2-verbatim).
// Phase 2: u/v with av from GLOBAL (4 addrs/wave, L1 broadcast, VMEM pipe),
//   bv from LDS (3 ds_read_b128/mq/wave — was 8), w via uniform s_load,
//   (u,v) packed into v_pk_fma_f32 — per-component order identical to R2.
// ---------------------------------------------------------------------------
__global__ __launch_bounds__(256) void grn_main(
    const float* __restrict__ AiB, const float* __restrict__ Bjp,
    const _Float16* __restrict__ Yh, const _Float16* __restrict__ Xh,
    const float* __restrict__ Wd,  const float* __restrict__ b2,
    const float* __restrict__ bb,  float* __restrict__ out)
{
    const int gj = blockIdx.x & 15;
    const int gi = blockIdx.x >> 4;
    const int tx = threadIdx.x;
    const int it = tx >> 4;   // 0..15 -> i rows it+{0,16,32}
    const int jt = tx & 15;   // 0..15 -> j cols jt+{0,16,32}

    __shared__ _Float16 sLh[TILE * LDPH];  // Yh tile (13.1 KB)
    __shared__ _Float16 sRh[TILE * LDPH];  // Xh tile (13.1 KB)
    __shared__ float    sR [TILE * LDP];   // Bjp tile (25.3 KB)

    load_tile_f16(sLh, Yh + gi * TILE * H, tx);
    load_tile_f16(sRh, Xh + gj * TILE * H, tx);
    load_tile_f32(sR,  Bjp + gj * TILE * H, tx);
    __syncthreads();

    // ---- phase 1: affinity (f16 storage, f32 accumulate via v_dot2) ----
    float aff[3][3] = {};
    #pragma unroll 2
    for (int q = 0; q < H / 8; ++q) {
        h8 yv[3], xv[3];
        #pragma unroll
        for (int r = 0; r < 3; ++r) yv[r] = *(const h8*)&sLh[(it + 16 * r) * LDPH + q * 8];
        #pragma unroll
        for (int c = 0; c < 3; ++c) xv[c] = *(const h8*)&sRh[(jt + 16 * c) * LDPH + q * 8];
        #pragma unroll
        for (int r = 0; r < 3; ++r)
            #pragma unroll
            for (int c = 0; c < 3; ++c)
                #pragma unroll
                for (int p = 0; p < 4; ++p) {
#if __has_builtin(__builtin_amdgcn_fdot2)
                    aff[r][c] = __builtin_amdgcn_fdot2(hpair(yv[r], p), hpair(xv[c], p),
                                                       aff[r][c], false);
#else
                    h2 a = hpair(yv[r], p), b = hpair(xv[c], p);
                    aff[r][c] = fmaf((float)a.x, (float)b.x, aff[r][c]);
                    aff[r][c] = fmaf((float)a.y, (float)b.y, aff[r][c]);
#endif
                }
    }

    // ---- phase 2: logit differences (per-component math bit-identical to R2) ----
    const f2 uv0 = {b2[0] - b2[2], b2[0] - b2[1]};   // {u0, v0}
    f2 uv[3][3];
    #pragma unroll
    for (int r = 0; r < 3; ++r)
        #pragma unroll
        for (int c = 0; c < 3; ++c) uv[r][c] = uv0;

    const float* aRow = AiB + (gi * TILE + it) * H;  // rows +0, +16*H, +32*H
    const float4* Wduv = (const float4*)Wd;          // interleaved {u,v} pairs

    const f2 zero2 = {0.0f, 0.0f};
    #pragma unroll 4
    for (int mq = 0; mq < H / 4; ++mq) {
        // uniform -> s_load; {u,v} weights for m0,m1 then m2,m3
        float4 wq0 = Wduv[2 * mq];
        float4 wq1 = Wduv[2 * mq + 1];
        float4 av[3], bv[3];
        #pragma unroll
        for (int r = 0; r < 3; ++r) av[r] = *(const float4*)(aRow + r * 16 * H + mq * 4);
        #pragma unroll
        for (int c = 0; c < 3; ++c) bv[c] = *(const float4*)&sR[(jt + 16 * c) * LDP + mq * 4];
        #pragma unroll
        for (int r = 0; r < 3; ++r) {
            f2 a01 = {av[r].x, av[r].y};
            f2 a23 = {av[r].z, av[r].w};
            #pragma unroll
            for (int c = 0; c < 3; ++c) {
                f2 b01 = {bv[c].x, bv[c].y};
                f2 b23 = {bv[c].z, bv[c].w};
                // packed relu(a+b): elementwise -> bit-identical to scalar
                f2 h01 = __builtin_elementwise_max(a01 + b01, zero2);
                f2 h23 = __builtin_elementwise_max(a23 + b23, zero2);
                // v_pk_fma_f32: x-lane = u chain, y-lane = v chain, R2 order
                f2 t = uv[r][c];
                t = (f2){h01.x, h01.x} * (f2){wq0.x, wq0.y} + t;   // m0
                t = (f2){h01.y, h01.y} * (f2){wq0.z, wq0.w} + t;   // m1
                t = (f2){h23.x, h23.x} * (f2){wq1.x, wq1.y} + t;   // m2
                t = (f2){h23.y, h23.y} * (f2){wq1.z, wq1.w} + t;   // m3
                uv[r][c] = t;
            }
        }
    }

    // ---- epilogue: sign select, bilinear bias, zero diagonal ----
    const float bbv = bb[0];
    #pragma unroll
    for (int r = 0; r < 3; ++r) {
        const int i = gi * TILE + it + 16 * r;
        #pragma unroll
        for (int c = 0; c < 3; ++c) {
            const int j = gj * TILE + jt + 16 * c;
            float A = aff[r][c] + bbv;
            float uu = uv[r][c].x, vv = uv[r][c].y;
            // cls0: vv>=0 && uu>=0 -> +A ; cls2: uu<0 && uu<vv -> -A ; else 0
            float s = (uu >= 0.0f && vv >= 0.0f) ? A
                    : ((uu < 0.0f && uu < vv) ? -A : 0.0f);
            if (i == j) s = 0.0f;
            out[i * N_GENES + j] = s;
        }
    }
}

extern "C" void kernel_launch(void* const* d_in, const int* in_sizes, int n_in,
                              void* d_out, int out_size, void* d_ws, size_t ws_size,
                              hipStream_t stream)
{
    const float* X  = (const float*)d_in[0];  // [768,128]
    const float* W1 = (const float*)d_in[1];  // [128,256]
    const float* b1 = (const float*)d_in[2];  // [128]
    const float* W2 = (const float*)d_in[3];  // [3,128]
    const float* b2 = (const float*)d_in[4];  // [3]
    const float* Wb = (const float*)d_in[5];  // [1,128,128]
    const float* bb = (const float*)d_in[6];  // [1]
    float* out = (float*)d_out;

    float* ws = (float*)d_ws;
    float*    AiB = ws;                               // 768*128 f32
    float*    Bjp = ws + N_GENES * H;                 // 768*128 f32
    float*    Wd  = ws + 2 * N_GENES * H;             // 256 f32, {u,v} interleaved
    _Float16* Yh  = (_Float16*)(ws + 2 * N_GENES * H + 256);   // 768*128 f16
    _Float16* Xh  = Yh + N_GENES * H;                           // 768*128 f16

    grn_pre <<<N_GENES / 3, 128, 0, stream>>>(X, W1, b1, Wb, W2, AiB, Bjp, Wd, Yh, Xh);
    grn_main<<<256,         256, 0, stream>>>(AiB, Bjp, Yh, Xh, Wd, b2, bb, out);
}